// Round 9
// baseline (56.994 us; speedup 1.0000x reference)
//
#include <hip/hip_runtime.h>
#include <math.h>

// Problem constants: B=4, C=128, H=W=96, E=4, C8=16, scale=2 (baked in)
#define Bn 4
#define Cc 128
#define Hh 96
#define Ww 96
#define H2c 192
#define W2c 192
#define HW (Hh*Ww)

// Workspace layout:
//   floats: [WC_OFF,+4*2048) Wc_t[cls][c][o] ; [WE_OFF,+4*2048) We[cls][c][o]
//           [TAP_OFF,+16) per-class {tx,ty,Dx,Dy}
//   ushort (bf16) at float-offset M_OFF: M[cls][c_out][128]  (folded We*Wc+I)
#define WC_OFF 0
#define WE_OFF (4*2048)
#define TAP_OFF (8*2048)
#define M_OFF  16640          // float offset; byte 66560 (16B aligned)

typedef float  f32x4  __attribute__((ext_vector_type(4)));
typedef short  s16x8  __attribute__((ext_vector_type(8)));

__device__ __forceinline__ unsigned f2bf(float f) {
    unsigned u = __float_as_uint(f);
    return (u + 0x7FFFu + ((u >> 16) & 1u)) >> 16;   // RNE to bf16
}

// ---------------------------------------------------------------------------
// K1: per-class tiny MLP -> routing/offsets; mix expert weights; tap constants.
__global__ __launch_bounds__(256) void k1_mix(
    const float* __restrict__ wcomp, const float* __restrict__ wexp,
    const float* __restrict__ bw1, const float* __restrict__ bb1,
    const float* __restrict__ bw2, const float* __restrict__ bb2,
    const float* __restrict__ rw,  const float* __restrict__ rb,
    const float* __restrict__ ow,  const float* __restrict__ ob,
    float* __restrict__ ws)
{
    __shared__ float e1[64], e2[64], rr[4], of[2];
    const int tid   = threadIdx.x;
    const int cls   = blockIdx.x >> 4;
    const int chunk = blockIdx.x & 15;
    const float chv = (cls & 2) ? 0.25f : -0.25f;
    const float cwv = (cls & 1) ? 0.25f : -0.25f;

    if (tid < 64) {
        float h = bw1[tid*3+0]*0.5f + bw1[tid*3+1]*chv + bw1[tid*3+2]*cwv + bb1[tid];
        e1[tid] = fmaxf(h, 0.f);
    }
    __syncthreads();
    if (tid < 64) {
        float s = bb2[tid];
        for (int i = 0; i < 64; ++i) s += bw2[tid*64+i]*e1[i];
        e2[tid] = fmaxf(s, 0.f);
    }
    __syncthreads();
    if (tid < 6) {
        if (tid < 4) {
            float s = rb[tid];
            for (int i = 0; i < 64; ++i) s += rw[tid*64+i]*e2[i];
            rr[tid] = 1.f/(1.f+expf(-s));
        } else {
            const int d = tid - 4;
            float s = ob[d];
            for (int i = 0; i < 64; ++i) s += ow[d*64+i]*e2[i];
            of[d] = s;
        }
    }
    __syncthreads();
    const float r0 = rr[0], r1 = rr[1], r2 = rr[2], r3 = rr[3];

    if (tid < 128) {
        const int idx = chunk*128 + tid;
        const int o = idx >> 7, c = idx & 127;
        const float v = r0*wcomp[idx] + r1*wcomp[2048+idx]
                      + r2*wcomp[4096+idx] + r3*wcomp[6144+idx];
        ws[WC_OFF + cls*2048 + c*16 + o] = v;     // transposed [c][o]
    } else {
        const int idx = chunk*128 + (tid - 128);
        ws[WE_OFF + cls*2048 + idx] =             // native [c][o]
            r0*wexp[idx] + r1*wexp[2048+idx] + r2*wexp[4096+idx] + r3*wexp[6144+idx];
    }
    if (chunk == 0 && tid == 0) {
        const float fx = cwv + of[0];
        const float fy = chv + of[1];
        const float Dx = floorf(fx), Dy = floorf(fy);
        ws[TAP_OFF + cls*4 + 0] = fx - Dx;
        ws[TAP_OFF + cls*4 + 1] = fy - Dy;
        ws[TAP_OFF + cls*4 + 2] = Dx;
        ws[TAP_OFF + cls*4 + 3] = Dy;
    }
}

// ---------------------------------------------------------------------------
// K1b: fold M[cls] = We_mix * Wc_mix + I, store bf16 row-major [c_out][c_in].
__global__ __launch_bounds__(256) void k1b_fold(
    const float* __restrict__ wsr, unsigned short* __restrict__ Mw)
{
    const int t   = blockIdx.x*256 + threadIdx.x;    // 0..16383
    const int cls = t >> 12;
    const int rem = t & 4095;
    const int co  = rem >> 5;            // c_out 0..127
    const int ci0 = (rem & 31) * 4;      // c_in base
    const float* we = wsr + WE_OFF + cls*2048 + co*16;

    float m[4];
    #pragma unroll
    for (int q = 0; q < 4; ++q) {
        const float* wc = wsr + WC_OFF + cls*2048 + (ci0+q)*16;
        float s = 0.f;
        #pragma unroll
        for (int o = 0; o < 16; ++o) s += we[o]*wc[o];
        if (co == ci0 + q) s += 1.f;     // residual identity folded in
        m[q] = s;
    }
    uint2 v;
    v.x = f2bf(m[0]) | (f2bf(m[1]) << 16);
    v.y = f2bf(m[2]) | (f2bf(m[3]) << 16);
    *reinterpret_cast<uint2*>(Mw + (size_t)cls*16384 + co*128 + ci0) = v;
}

// Edge remap (verified rounds 1-8).
__device__ __forceinline__ void remap_axis(int c0, int last, float w0, float w1,
                                           int& base, float& a0, float& a1)
{
    base = min(max(c0, 0), last - 1);
    if (c0 >= 0 && c0 < last) { a0 = w0;  a1 = w1;  }
    else if (c0 == -1)        { a0 = w1;  a1 = 0.f; }
    else if (c0 == last)      { a0 = 0.f; a1 = w0;  }
    else                      { a0 = 0.f; a1 = 0.f; }
}

// ---------------------------------------------------------------------------
// K2: fused gather + M@fea via MFMA (operand-swapped: D[px][ch]).
// 2304 blocks x 256 threads (4 waves). Block = 64 contiguous FULL-RES x of
// one full-res row yg (both x-parities). LDS rows partitioned by parity:
// rows 0-31 = even-x pixels (xg_local=2s), rows 32-63 = odd (2(s-32)+1) so
// each 16-row A-tile is class-pure (B=M uniform, no masking). Producer =
// depth-2 pipelined 32-load batches fenced with sched_barrier. Store:
// even/odd tile accumulators interleaved in regs -> dwordx4, full lines.
__global__ __launch_bounds__(256, 4) void k2_mfma(
    const float* __restrict__ x, const float* __restrict__ wsr,
    const unsigned short* __restrict__ Mw, float* __restrict__ out)
{
    __shared__ __align__(16) unsigned short lF[64*128];   // 16 KB, swizzled

    const int tid = threadIdx.x;
    const int l   = tid & 63;
    const int grp = tid >> 6;

    // XCD swizzle: 2304 = 8 XCDs * 288; each XCD gets 96 consecutive rows of
    // one batch (x slice ~2.4MB -> L2-resident).
    const int n  = blockIdx.x;
    const int g  = (n & 7)*288 + (n >> 3);
    const int b  = g / 576;
    const int r  = g % 576;
    const int yg = r / 3;          // full-res row 0..191
    const int xt = r % 3;          // 64-px x-strip

    // ---- producer lane -> pixel: s<32 even-x, s>=32 odd-x ----
    const int s   = l;
    const int par = s >> 5;
    const int i   = xt*32 + (s & 31);   // half-res col
    const int j   = yg >> 1;            // half-res row
    const int cls = ((yg & 1) << 1) | par;

    const float tx = wsr[TAP_OFF + cls*4 + 0];
    const float ty = wsr[TAP_OFF + cls*4 + 1];
    const int   Dx = (int)wsr[TAP_OFF + cls*4 + 2];
    const int   Dy = (int)wsr[TAP_OFF + cls*4 + 3];
    int cb, rbw; float ax0, ax1, ay0, ay1;
    remap_axis(i + Dx, Ww - 1, 1.f - tx, tx, cb,  ax0, ax1);
    remap_axis(j + Dy, Hh - 1, 1.f - ty, ty, rbw, ay0, ay1);
    const float w00 = ay0*ax0, w01 = ay0*ax1, w10 = ay1*ax0, w11 = ay1*ax1;
    const float* xb = x + (size_t)b*Cc*HW + rbw*Ww + cb;
    const int chbase = grp*32;

#define LOADB(t0,t1,t2,t3,base) \
    _Pragma("unroll") \
    for (int k = 0; k < 8; ++k) { \
        const float* p = xb + (size_t)(chbase + (base) + k)*HW; \
        t0[k] = p[0]; t1[k] = p[1]; t2[k] = p[Ww]; t3[k] = p[Ww+1]; \
    }

#define CONSB(t0,t1,t2,t3,base) \
    _Pragma("unroll") \
    for (int k = 0; k < 8; k += 4) { \
        const float f0 = w00*t0[k  ] + w01*t1[k  ] + w10*t2[k  ] + w11*t3[k  ]; \
        const float f1 = w00*t0[k+1] + w01*t1[k+1] + w10*t2[k+1] + w11*t3[k+1]; \
        const float f2 = w00*t0[k+2] + w01*t1[k+2] + w10*t2[k+2] + w11*t3[k+2]; \
        const float f3 = w00*t0[k+3] + w01*t1[k+3] + w10*t2[k+3] + w11*t3[k+3]; \
        uint2 v; \
        v.x = f2bf(f0) | (f2bf(f1) << 16); \
        v.y = f2bf(f2) | (f2bf(f3) << 16); \
        const int c = chbase + (base) + k; \
        int byte = l*256 + c*2; \
        byte ^= (l & 7) << 4; \
        *reinterpret_cast<uint2*>(reinterpret_cast<char*>(lF) + byte) = v; \
    }

    // ---- depth-2 pipelined producer: 4 batches of 8 ch x 4 taps ----
    {
        float a0[8], a1[8], a2[8], a3[8];
        float b0[8], b1[8], b2[8], b3[8];
        LOADB(a0,a1,a2,a3, 0)
        LOADB(b0,b1,b2,b3, 8)
        __builtin_amdgcn_sched_barrier(0);
        CONSB(a0,a1,a2,a3, 0)
        LOADB(a0,a1,a2,a3, 16)
        __builtin_amdgcn_sched_barrier(0);
        CONSB(b0,b1,b2,b3, 8)
        LOADB(b0,b1,b2,b3, 24)
        __builtin_amdgcn_sched_barrier(0);
        CONSB(a0,a1,a2,a3, 16)
        __builtin_amdgcn_sched_barrier(0);
        CONSB(b0,b1,b2,b3, 24)
    }
    __syncthreads();

    // ---- GEMM: D[64px x 128ch] = fea^T @ M^T, per-parity phases ----
    f32x4 acc[2][4];
    #pragma unroll
    for (int t = 0; t < 2; ++t)
        #pragma unroll
        for (int nn = 0; nn < 4; ++nn) acc[t][nn] = (f32x4){0.f, 0.f, 0.f, 0.f};

    const int lo = l & 15, hi = l >> 4;
    #pragma unroll
    for (int ph = 0; ph < 2; ++ph) {           // 0: even tiles nn=0,1; 1: odd nn=2,3
        const unsigned short* Mc = Mw + (size_t)(((yg & 1) << 1) | ph)*16384;
        s16x8 mf[2][4];
        #pragma unroll
        for (int t = 0; t < 2; ++t)
            #pragma unroll
            for (int kk = 0; kk < 4; ++kk)
                mf[t][kk] = *reinterpret_cast<const s16x8*>(
                    Mc + (32*grp + 16*t + lo)*128 + kk*32 + hi*8);
        #pragma unroll
        for (int kk = 0; kk < 4; ++kk) {
            #pragma unroll
            for (int q = 0; q < 2; ++q) {
                const int nn = ph*2 + q;
                const int row = nn*16 + lo;
                int byte = row*256 + kk*64 + hi*16;
                byte ^= (row & 7) << 4;
                const s16x8 af = *reinterpret_cast<const s16x8*>(
                    reinterpret_cast<const char*>(lF) + byte);
                acc[0][nn] = __builtin_amdgcn_mfma_f32_16x16x32_bf16(af, mf[0][kk], acc[0][nn], 0, 0, 0);
                acc[1][nn] = __builtin_amdgcn_mfma_f32_16x16x32_bf16(af, mf[1][kk], acc[1][nn], 0, 0, 0);
            }
        }
    }

    // ---- store: interleave even/odd tiles -> contiguous dwordx4 ----
    // D(t,nn): ch = 32grp+16t+lo; rows -> xg_local: even tile p: 32p+8hi+2r,
    // odd tile p+2: 32p+8hi+2r+1. Interleaved pairs cover 8 consecutive xg.
    #pragma unroll
    for (int t = 0; t < 2; ++t) {
        const int ch = 32*grp + 16*t + lo;
        #pragma unroll
        for (int p = 0; p < 2; ++p) {
            const f32x4 e = acc[t][p], o = acc[t][p+2];
            const f32x4 v0 = {e[0], o[0], e[1], o[1]};
            const f32x4 v1 = {e[2], o[2], e[3], o[3]};
            float* op = out + ((size_t)(b*Cc + ch)*H2c + yg)*W2c
                      + xt*64 + p*32 + hi*8;
            *reinterpret_cast<f32x4*>(op)     = v0;
            *reinterpret_cast<f32x4*>(op + 4) = v1;
        }
    }
#undef LOADB
#undef CONSB
}

extern "C" void kernel_launch(void* const* d_in, const int* in_sizes, int n_in,
                              void* d_out, int out_size, void* d_ws, size_t ws_size,
                              hipStream_t stream) {
    const float* x     = (const float*)d_in[0];
    const float* wcomp = (const float*)d_in[1];
    const float* wexp  = (const float*)d_in[2];
    const float* bw1   = (const float*)d_in[3];
    const float* bb1   = (const float*)d_in[4];
    const float* bw2   = (const float*)d_in[5];
    const float* bb2   = (const float*)d_in[6];
    const float* rw    = (const float*)d_in[7];
    const float* rb    = (const float*)d_in[8];
    const float* ow    = (const float*)d_in[9];
    const float* ob    = (const float*)d_in[10];
    float* out = (float*)d_out;
    float* ws  = (float*)d_ws;
    unsigned short* Mw = (unsigned short*)(ws + M_OFF);   // ~194 KB total used

    k1_mix<<<64, 256, 0, stream>>>(wcomp, wexp, bw1, bb1, bw2, bb2, rw, rb, ow, ob, ws);
    k1b_fold<<<64, 256, 0, stream>>>(ws, Mw);
    k2_mfma<<<2304, 256, 0, stream>>>(x, ws, Mw, out);
}

// Round 10
// 54.645 us; speedup vs baseline: 1.0430x; 1.0430x over previous
//
#include <hip/hip_runtime.h>
#include <math.h>

// Problem constants: B=4, C=128, H=W=96, E=4, C8=16, scale=2 (baked in)
#define Bn 4
#define Cc 128
#define Hh 96
#define Ww 96
#define H2c 192
#define W2c 192
#define HW (Hh*Ww)

// Workspace layout (floats):
//   [WC_OFF, +4*2048)  Wc_t[cls][c][o]  (transposed: c-major, 16 o contiguous)
//   [WE_OFF, +4*2048)  We  [cls][c][o]  (native wexp layout)
//   [TAP_OFF, +16)     per-class {tx, ty, Dx, Dy}
#define WC_OFF 0
#define WE_OFF (4*2048)
#define TAP_OFF (8*2048)

// quad_perm broadcast: every lane receives quad-lane T's value (VALU pipe, no LDS)
#define QB(v, CTRL) __builtin_bit_cast(float, \
    __builtin_amdgcn_mov_dpp(__builtin_bit_cast(int, (v)), (CTRL), 0xF, 0xF, true))

// ---------------------------------------------------------------------------
// K1: per-class tiny MLP -> routing/offsets; mix expert weights; tap constants.
__global__ __launch_bounds__(256) void k1_mix(
    const float* __restrict__ wcomp, const float* __restrict__ wexp,
    const float* __restrict__ bw1, const float* __restrict__ bb1,
    const float* __restrict__ bw2, const float* __restrict__ bb2,
    const float* __restrict__ rw,  const float* __restrict__ rb,
    const float* __restrict__ ow,  const float* __restrict__ ob,
    float* __restrict__ ws)
{
    __shared__ float e1[64], e2[64], rr[4], of[2];
    const int tid   = threadIdx.x;
    const int cls   = blockIdx.x >> 4;   // pcy*2 + pcx
    const int chunk = blockIdx.x & 15;
    const float chv = (cls & 2) ? 0.25f : -0.25f;  // row fractional coord
    const float cwv = (cls & 1) ? 0.25f : -0.25f;  // col fractional coord

    if (tid < 64) {
        float h = bw1[tid*3+0]*0.5f + bw1[tid*3+1]*chv + bw1[tid*3+2]*cwv + bb1[tid];
        e1[tid] = fmaxf(h, 0.f);
    }
    __syncthreads();
    if (tid < 64) {
        float s = bb2[tid];
        for (int i = 0; i < 64; ++i) s += bw2[tid*64+i]*e1[i];
        e2[tid] = fmaxf(s, 0.f);
    }
    __syncthreads();
    if (tid < 6) {
        if (tid < 4) {
            float s = rb[tid];
            for (int i = 0; i < 64; ++i) s += rw[tid*64+i]*e2[i];
            rr[tid] = 1.f/(1.f+expf(-s));
        } else {
            const int d = tid - 4;
            float s = ob[d];
            for (int i = 0; i < 64; ++i) s += ow[d*64+i]*e2[i];
            of[d] = s;
        }
    }
    __syncthreads();
    const float r0 = rr[0], r1 = rr[1], r2 = rr[2], r3 = rr[3];

    if (tid < 128) {
        // Wc: source [o][c] (idx = o*128+c), dest transposed [c][o]
        const int idx = chunk*128 + tid;
        const int o = idx >> 7, c = idx & 127;
        const float v = r0*wcomp[idx] + r1*wcomp[2048+idx]
                      + r2*wcomp[4096+idx] + r3*wcomp[6144+idx];
        ws[WC_OFF + cls*2048 + c*16 + o] = v;
    } else {
        // We: native [c][o] layout, straight copy of the mix
        const int idx = chunk*128 + (tid - 128);
        ws[WE_OFF + cls*2048 + idx] =
            r0*wexp[idx] + r1*wexp[2048+idx] + r2*wexp[4096+idx] + r3*wexp[6144+idx];
    }
    if (chunk == 0 && tid == 0) {
        const float fx = cwv + of[0];
        const float fy = chv + of[1];
        const float Dx = floorf(fx), Dy = floorf(fy);
        ws[TAP_OFF + cls*4 + 0] = fx - Dx;
        ws[TAP_OFF + cls*4 + 1] = fy - Dy;
        ws[TAP_OFF + cls*4 + 2] = Dx;
        ws[TAP_OFF + cls*4 + 3] = Dy;
    }
}

// Edge remap: taps at c0, c0+1 clamped to 2-wide window [base, base+1], with
// zero-padding folded into the two weights. (Verified rounds 1-9.)
__device__ __forceinline__ void remap_axis(int c0, int last, float w0, float w1,
                                           int& base, float& a0, float& a1)
{
    base = min(max(c0, 0), last - 1);
    if (c0 >= 0 && c0 < last) { a0 = w0;  a1 = w1;  }
    else if (c0 == -1)        { a0 = w1;  a1 = 0.f; }
    else if (c0 == last)      { a0 = 0.f; a1 = w0;  }
    else                      { a0 = 0.f; a1 = 0.f; }
}

// ---------------------------------------------------------------------------
// Fused compress+expand, class-pure blocks (round-4 structure) + DPP weights.
// 2304 blocks x 256 threads (4 waves). Block = 64 consecutive pixels of the
// 96x96 half-res grid of ONE class; wave g owns channels [g*32, g*32+32).
// Weight access: lane reads ONE ds_read_b128 (its o-quarter, quarter = l&3),
// the quad exchanges quarters via v_mov_dpp quad_perm broadcasts (VALU pipe).
// Cuts LDS reads 4x vs round 4; everything else identical.
__global__ __launch_bounds__(256) void k2_fused(
    const float* __restrict__ x, const float* __restrict__ wsr,
    float* __restrict__ out)
{
    __shared__ __align__(16) float lWc[2048];      // [c][o] 8 KB (this class)
    __shared__ __align__(16) float lWe[2048];      // [c][o] 8 KB
    __shared__ float lPart[4*16*64];               // [g][o][xl] 16 KB

    const int tid = threadIdx.x;
    const int xl  = tid & 63;
    const int grp = tid >> 6;
    const int ql  = (xl & 3) * 4;     // this lane's o-quarter offset

    // XCD-paired swizzle: 2304 = 8 XCDs * 288 slots; the 4 classes of a tile
    // land consecutively on ONE XCD (stride-2 stores merge, x rows shared).
    const int n = blockIdx.x;
    const int w = (n & 7) * 288 + (n >> 3);
    const int px = w & 1, py = (w >> 1) & 1;
    const int w2 = w >> 2;            // 0..575
    const int tile = w2 % 144;        // spatial tile
    const int b    = w2 / 144;
    const int cls  = (py << 1) | px;

    // stage this class's weights (coalesced float4, 2 per thread each)
    {
        const float4* sc = reinterpret_cast<const float4*>(wsr + WC_OFF + cls*2048);
        const float4* se = reinterpret_cast<const float4*>(wsr + WE_OFF + cls*2048);
        float4* dc = reinterpret_cast<float4*>(lWc);
        float4* de = reinterpret_cast<float4*>(lWe);
        dc[tid] = sc[tid]; dc[tid+256] = sc[tid+256];
        de[tid] = se[tid]; de[tid+256] = se[tid+256];
    }

    // pixel decode: flat index in 96x96 half-res grid
    const int idx = tile*64 + xl;
    const int j = idx / 96;           // half-res row
    const int i = idx - j*96;         // half-res col

    const float tx = wsr[TAP_OFF + cls*4 + 0];
    const float ty = wsr[TAP_OFF + cls*4 + 1];
    const int   Dx = (int)wsr[TAP_OFF + cls*4 + 2];
    const int   Dy = (int)wsr[TAP_OFF + cls*4 + 3];
    int cb, rbw; float ax0, ax1, ay0, ay1;
    remap_axis(i + Dx, Ww - 1, 1.f - tx, tx, cb,  ax0, ax1);
    remap_axis(j + Dy, Hh - 1, 1.f - ty, ty, rbw, ay0, ay1);
    const float w00 = ay0*ax0, w01 = ay0*ax1, w10 = ay1*ax0, w11 = ay1*ax1;
    const float* xb = x + (size_t)b*Cc*HW + rbw*Ww + cb;
    __syncthreads();

    // ---- P1: partial compress over this wave's 32 channels; fea -> VGPRs ----
    float comp[16];
    #pragma unroll
    for (int o = 0; o < 16; ++o) comp[o] = 0.f;
    float fea[32];

    #pragma unroll
    for (int kk = 0; kk < 32; ++kk) {
        const int c = grp*32 + kk;
        const float* p = xb + (size_t)c*HW;
        const float f = w00*p[0] + w01*p[1] + w10*p[Ww] + w11*p[Ww+1];
        fea[kk] = f;
        // lane reads its quarter; quad-lane t holds Wc[c][4t..4t+4)
        const float4 wq = *reinterpret_cast<const float4*>(lWc + c*16 + ql);
        comp[ 0] += QB(wq.x,0x00)*f; comp[ 1] += QB(wq.y,0x00)*f;
        comp[ 2] += QB(wq.z,0x00)*f; comp[ 3] += QB(wq.w,0x00)*f;
        comp[ 4] += QB(wq.x,0x55)*f; comp[ 5] += QB(wq.y,0x55)*f;
        comp[ 6] += QB(wq.z,0x55)*f; comp[ 7] += QB(wq.w,0x55)*f;
        comp[ 8] += QB(wq.x,0xAA)*f; comp[ 9] += QB(wq.y,0xAA)*f;
        comp[10] += QB(wq.z,0xAA)*f; comp[11] += QB(wq.w,0xAA)*f;
        comp[12] += QB(wq.x,0xFF)*f; comp[13] += QB(wq.y,0xFF)*f;
        comp[14] += QB(wq.z,0xFF)*f; comp[15] += QB(wq.w,0xFF)*f;
    }
    #pragma unroll
    for (int o = 0; o < 16; ++o) lPart[(grp*16 + o)*64 + xl] = comp[o];
    __syncthreads();

    // ---- cross-wave reduce into g=0 region (same-thread RMW per slot) ----
    #pragma unroll
    for (int jj = 0; jj < 4; ++jj) {
        const int o = grp*4 + jj;
        const float s = lPart[(o     )*64 + xl] + lPart[(16 + o)*64 + xl]
                      + lPart[(32 + o)*64 + xl] + lPart[(48 + o)*64 + xl];
        lPart[o*64 + xl] = s;
    }
    __syncthreads();

    // ---- P2: expand + residual (fea from regs), DPP-broadcast We ----
    float cf[16];
    #pragma unroll
    for (int o = 0; o < 16; ++o) cf[o] = lPart[o*64 + xl];

    const int xg = 2*i + px;
    const int yg = 2*j + py;
    float* op = out + ((size_t)(b*Cc)*H2c + yg)*W2c + xg;

    #pragma unroll
    for (int kk = 0; kk < 32; ++kk) {
        const int c = grp*32 + kk;
        const float4 wq = *reinterpret_cast<const float4*>(lWe + c*16 + ql);
        float acc = fea[kk]
            + QB(wq.x,0x00)*cf[ 0] + QB(wq.y,0x00)*cf[ 1]
            + QB(wq.z,0x00)*cf[ 2] + QB(wq.w,0x00)*cf[ 3]
            + QB(wq.x,0x55)*cf[ 4] + QB(wq.y,0x55)*cf[ 5]
            + QB(wq.z,0x55)*cf[ 6] + QB(wq.w,0x55)*cf[ 7]
            + QB(wq.x,0xAA)*cf[ 8] + QB(wq.y,0xAA)*cf[ 9]
            + QB(wq.z,0xAA)*cf[10] + QB(wq.w,0xAA)*cf[11]
            + QB(wq.x,0xFF)*cf[12] + QB(wq.y,0xFF)*cf[13]
            + QB(wq.z,0xFF)*cf[14] + QB(wq.w,0xFF)*cf[15];
        op[(size_t)c*(H2c*W2c)] = acc;
    }
}

extern "C" void kernel_launch(void* const* d_in, const int* in_sizes, int n_in,
                              void* d_out, int out_size, void* d_ws, size_t ws_size,
                              hipStream_t stream) {
    const float* x     = (const float*)d_in[0];
    const float* wcomp = (const float*)d_in[1];
    const float* wexp  = (const float*)d_in[2];
    const float* bw1   = (const float*)d_in[3];
    const float* bb1   = (const float*)d_in[4];
    const float* bw2   = (const float*)d_in[5];
    const float* bb2   = (const float*)d_in[6];
    const float* rw    = (const float*)d_in[7];
    const float* rb    = (const float*)d_in[8];
    const float* ow    = (const float*)d_in[9];
    const float* ob    = (const float*)d_in[10];
    float* out = (float*)d_out;
    float* ws  = (float*)d_ws;   // ~66 KB

    k1_mix<<<64, 256, 0, stream>>>(wcomp, wexp, bw1, bb1, bw2, bb2, rw, rb, ow, ob, ws);
    k2_fused<<<2304, 256, 0, stream>>>(x, ws, out);
}

// Round 11
// 42.966 us; speedup vs baseline: 1.3265x; 1.2718x over previous
//
#include <hip/hip_runtime.h>
#include <math.h>

// Problem constants: B=4, C=128, H=W=96, E=4, C8=16, scale=2 (baked in)
#define Bn 4
#define Cc 128
#define Hh 96
#define Ww 96
#define H2c 192
#define W2c 192
#define HW (Hh*Ww)
#define HW2 (H2c*W2c)

// Workspace layout:
//   floats: [WC_OFF,+4*2048) Wc_t[cls][c][o] ; [WE_OFF,+4*2048) We[cls][c][o]
//           [TAP_OFF,+16) per-class {tx,ty,Dx,Dy}
//   ushort (bf16) at float-offset M_OFF: M[cls][c_out][128]  (folded We*Wc+I)
#define WC_OFF 0
#define WE_OFF (4*2048)
#define TAP_OFF (8*2048)
#define M_OFF  16640          // float offset; byte 66560 (16B aligned)

typedef float  f32x4  __attribute__((ext_vector_type(4)));
typedef short  s16x8  __attribute__((ext_vector_type(8)));

__device__ __forceinline__ unsigned f2bf(float f) {
    unsigned u = __float_as_uint(f);
    return (u + 0x7FFFu + ((u >> 16) & 1u)) >> 16;   // RNE to bf16
}

// global -> LDS DMA, 16B per lane. LDS dest = wave-uniform base + lane*16.
__device__ __forceinline__ void gload_lds16(const float* g, float* l) {
    __builtin_amdgcn_global_load_lds(
        (const __attribute__((address_space(1))) unsigned int*)g,
        (__attribute__((address_space(3))) unsigned int*)l,
        16, 0, 0);
}

// ---------------------------------------------------------------------------
// K1: per-class tiny MLP -> routing/offsets; mix expert weights; tap constants.
__global__ __launch_bounds__(256) void k1_mix(
    const float* __restrict__ wcomp, const float* __restrict__ wexp,
    const float* __restrict__ bw1, const float* __restrict__ bb1,
    const float* __restrict__ bw2, const float* __restrict__ bb2,
    const float* __restrict__ rw,  const float* __restrict__ rb,
    const float* __restrict__ ow,  const float* __restrict__ ob,
    float* __restrict__ ws)
{
    __shared__ float e1[64], e2[64], rr[4], of[2];
    const int tid   = threadIdx.x;
    const int cls   = blockIdx.x >> 4;
    const int chunk = blockIdx.x & 15;
    const float chv = (cls & 2) ? 0.25f : -0.25f;
    const float cwv = (cls & 1) ? 0.25f : -0.25f;

    if (tid < 64) {
        float h = bw1[tid*3+0]*0.5f + bw1[tid*3+1]*chv + bw1[tid*3+2]*cwv + bb1[tid];
        e1[tid] = fmaxf(h, 0.f);
    }
    __syncthreads();
    if (tid < 64) {
        float s = bb2[tid];
        for (int i = 0; i < 64; ++i) s += bw2[tid*64+i]*e1[i];
        e2[tid] = fmaxf(s, 0.f);
    }
    __syncthreads();
    if (tid < 6) {
        if (tid < 4) {
            float s = rb[tid];
            for (int i = 0; i < 64; ++i) s += rw[tid*64+i]*e2[i];
            rr[tid] = 1.f/(1.f+expf(-s));
        } else {
            const int d = tid - 4;
            float s = ob[d];
            for (int i = 0; i < 64; ++i) s += ow[d*64+i]*e2[i];
            of[d] = s;
        }
    }
    __syncthreads();
    const float r0 = rr[0], r1 = rr[1], r2 = rr[2], r3 = rr[3];

    if (tid < 128) {
        const int idx = chunk*128 + tid;
        const int o = idx >> 7, c = idx & 127;
        const float v = r0*wcomp[idx] + r1*wcomp[2048+idx]
                      + r2*wcomp[4096+idx] + r3*wcomp[6144+idx];
        ws[WC_OFF + cls*2048 + c*16 + o] = v;     // transposed [c][o]
    } else {
        const int idx = chunk*128 + (tid - 128);
        ws[WE_OFF + cls*2048 + idx] =             // native [c][o]
            r0*wexp[idx] + r1*wexp[2048+idx] + r2*wexp[4096+idx] + r3*wexp[6144+idx];
    }
    if (chunk == 0 && tid == 0) {
        const float fx = cwv + of[0];
        const float fy = chv + of[1];
        const float Dx = floorf(fx), Dy = floorf(fy);
        ws[TAP_OFF + cls*4 + 0] = fx - Dx;
        ws[TAP_OFF + cls*4 + 1] = fy - Dy;
        ws[TAP_OFF + cls*4 + 2] = Dx;
        ws[TAP_OFF + cls*4 + 3] = Dy;
    }
}

// ---------------------------------------------------------------------------
// K1b: fold M[cls] = We_mix * Wc_mix + I, store bf16 row-major [c_out][c_in].
__global__ __launch_bounds__(256) void k1b_fold(
    const float* __restrict__ wsr, unsigned short* __restrict__ Mw)
{
    const int t   = blockIdx.x*256 + threadIdx.x;    // 0..16383
    const int cls = t >> 12;
    const int rem = t & 4095;
    const int co  = rem >> 5;            // c_out 0..127
    const int ci0 = (rem & 31) * 4;      // c_in base
    const float* we = wsr + WE_OFF + cls*2048 + co*16;

    float m[4];
    #pragma unroll
    for (int q = 0; q < 4; ++q) {
        const float* wc = wsr + WC_OFF + cls*2048 + (ci0+q)*16;
        float s = 0.f;
        #pragma unroll
        for (int o = 0; o < 16; ++o) s += we[o]*wc[o];
        if (co == ci0 + q) s += 1.f;     // residual identity folded in
        m[q] = s;
    }
    uint2 v;
    v.x = f2bf(m[0]) | (f2bf(m[1]) << 16);
    v.y = f2bf(m[2]) | (f2bf(m[3]) << 16);
    *reinterpret_cast<uint2*>(Mw + (size_t)cls*16384 + co*128 + ci0) = v;
}

// Edge remap (verified rounds 1-10).
__device__ __forceinline__ void remap_axis(int c0, int last, float w0, float w1,
                                           int& base, float& a0, float& a1)
{
    base = min(max(c0, 0), last - 1);
    if (c0 >= 0 && c0 < last) { a0 = w0;  a1 = w1;  }
    else if (c0 == -1)        { a0 = w1;  a1 = 0.f; }
    else if (c0 == last)      { a0 = 0.f; a1 = w0;  }
    else                      { a0 = 0.f; a1 = 0.f; }
}

// ---------------------------------------------------------------------------
// K2: wave-cooperative window staging + MFMA GEMM.
// 2304 blocks x 256 threads (4 waves). Block = 2 rows x 32 cols of the 96x96
// half-res grid of ONE class (no row wrap). Per channel, the 64 pixels' taps
// live in a 3-row x 40-col window; one global_load_lds_dwordx4 wave-instr
// stages TWO channels' windows (lane->slot linear). Taps then read from LDS
// (4 x b32 per channel, conflict-free). Consumer = r7 GEMM: A = M rows
// (folded We*Wc+I, bf16), B = fea bf16 swizzled tile, 32 MFMA, direct store.
__global__ __launch_bounds__(256) void k2_mfma(
    const float* __restrict__ x, const float* __restrict__ wsr,
    const unsigned short* __restrict__ Mw, float* __restrict__ out)
{
    __shared__ __align__(16) unsigned short lF[64*128];   // 16 KB fea tile (swizzled)
    __shared__ __align__(16) float lWin[4*2048];          // 32 KB: wave x 16ch x 128f

    const int tid = threadIdx.x;
    const int xl  = tid & 63;
    const int grp = tid >> 6;

    // XCD-paired swizzle: 2304 = 8 XCDs * 288; 4 classes of a tile consecutive
    // on one XCD (stride-2 stores merge in L2, x rows shared).
    const int n = blockIdx.x;
    const int w = (n & 7)*288 + (n >> 3);
    const int cls  = w & 3;
    const int px_  = cls & 1, py = (cls >> 1) & 1;
    const int rest = w >> 2;           // 0..575
    const int tile = rest % 144;
    const int b    = rest / 144;
    const int jt = tile/3, xs = tile - jt*3;
    const int j0 = jt*2, i0 = xs*32;   // class-tile origin (half-res)

    // ---- A fragments: M rows for this wave's 32 out-channels (L2-hot) ----
    const unsigned short* Mc = Mw + (size_t)cls*16384;
    const int lo = xl & 15, hi = xl >> 4;
    s16x8 a[2][4];
    #pragma unroll
    for (int t = 0; t < 2; ++t)
        #pragma unroll
        for (int kk = 0; kk < 4; ++kk)
            a[t][kk] = *reinterpret_cast<const s16x8*>(
                Mc + (32*grp + 16*t + lo)*128 + kk*32 + hi*8);

    // ---- per-pixel tap constants (lane = pixel slot: pr = s>>5, pc = s&31) ----
    const int pr = xl >> 5, pc = xl & 31;
    const int j = j0 + pr, i = i0 + pc;

    const float tx = wsr[TAP_OFF + cls*4 + 0];
    const float ty = wsr[TAP_OFF + cls*4 + 1];
    const int   Dx = (int)wsr[TAP_OFF + cls*4 + 2];
    const int   Dy = (int)wsr[TAP_OFF + cls*4 + 3];
    int basex, basey; float ax0, ax1, ay0, ay1;
    remap_axis(i + Dx, Ww - 1, 1.f - tx, tx, basex, ax0, ax1);
    remap_axis(j + Dy, Hh - 1, 1.f - ty, ty, basey, ay0, ay1);
    const float w00 = ay0*ax0, w01 = ay0*ax1, w10 = ay1*ax0, w11 = ay1*ax1;

    // window: rows clamp(jD+r) r=0..2, cols cs0..cs0+39 (16B-aligned start).
    // Per-pixel read offsets (floats, within a channel's 128-float region):
    //   slot pr row r*40; col index cidx = basex-cs0 in [0,38].
    const int c0  = i0 + Dx;
    const int cs0 = min(max(0, c0 & ~3), Ww - 40);
    const int cidx = basex - cs0;
    const int ro0 = pr*40 + cidx;
    const int ro1 = ro0 + 40;

    // this lane's staging assignment: sub-lane sl of half-wave loads float4
    // (row lr, col4 lq) of channel (pair base + xl>>5); lanes 30,31 duplicate.
    const int jD = j0 + Dy;
    const int sl = xl & 31;
    const int s2 = min(sl, 29);
    const int lr = s2 / 10, lq = s2 - lr*10;
    const int lrow = min(max(jD + lr, 0), Hh - 1);
    const float* gsrc = x + (size_t)b*Cc*HW + (size_t)lrow*Ww + cs0 + 4*lq;
    const int chsub = xl >> 5;         // 0 or 1 within the pair

    float* winw = lWin + grp*2048;     // this wave's 16-channel staging region

    // ---- two halves of 16 channels: DMA-stage, then fea+pack ----
    #pragma unroll
    for (int h = 0; h < 2; ++h) {
        #pragma unroll
        for (int p = 0; p < 8; ++p) {
            const int ch = grp*32 + h*16 + p*2 + chsub;
            gload_lds16(gsrc + (size_t)ch*HW, winw + p*256);
        }
        asm volatile("s_waitcnt vmcnt(0)" ::: "memory");
        __builtin_amdgcn_sched_barrier(0);
        #pragma unroll
        for (int cq = 0; cq < 4; ++cq) {
            float f[4];
            #pragma unroll
            for (int u = 0; u < 4; ++u) {
                const float* wc = winw + (cq*4 + u)*128;
                f[u] = w00*wc[ro0] + w01*wc[ro0+1] + w10*wc[ro1] + w11*wc[ro1+1];
            }
            uint2 v;
            v.x = f2bf(f[0]) | (f2bf(f[1]) << 16);
            v.y = f2bf(f[2]) | (f2bf(f[3]) << 16);
            const int c = grp*32 + h*16 + cq*4;
            int byte = xl*256 + c*2;
            byte ^= (xl & 7) << 4;
            *reinterpret_cast<uint2*>(reinterpret_cast<char*>(lF) + byte) = v;
        }
        if (h == 0) {   // WAR fence: half-0 tap reads done before DMA overwrites
            asm volatile("s_waitcnt lgkmcnt(0)" ::: "memory");
            __builtin_amdgcn_sched_barrier(0);
        }
    }
    __syncthreads();

    // ---- GEMM: D[128ch x 64px] = M @ fea (residual folded into M) ----
    f32x4 acc[2][4];
    #pragma unroll
    for (int t = 0; t < 2; ++t)
        #pragma unroll
        for (int nn = 0; nn < 4; ++nn) acc[t][nn] = (f32x4){0.f, 0.f, 0.f, 0.f};

    #pragma unroll
    for (int kk = 0; kk < 4; ++kk) {
        #pragma unroll
        for (int nn = 0; nn < 4; ++nn) {
            int byte = (nn*16 + lo)*256 + kk*64 + hi*16;
            byte ^= (lo & 7) << 4;
            const s16x8 bf = *reinterpret_cast<const s16x8*>(
                reinterpret_cast<const char*>(lF) + byte);
            acc[0][nn] = __builtin_amdgcn_mfma_f32_16x16x32_bf16(a[0][kk], bf, acc[0][nn], 0, 0, 0);
            acc[1][nn] = __builtin_amdgcn_mfma_f32_16x16x32_bf16(a[1][kk], bf, acc[1][nn], 0, 0, 0);
        }
    }

    // ---- store (r7 pattern: per-lane dwords, stride-2 merge with partner) ----
    #pragma unroll
    for (int t = 0; t < 2; ++t)
        #pragma unroll
        for (int nn = 0; nn < 4; ++nn) {
            const int slot2 = nn*16 + lo;
            const int pr2 = slot2 >> 5, pc2 = slot2 & 31;
            const int yg = 2*(j0 + pr2) + py;
            const int xg = 2*(i0 + pc2) + px_;
            const int ch0 = 32*grp + 16*t + hi*4;
            float* op = out + ((size_t)(b*Cc + ch0)*H2c + yg)*W2c + xg;
            #pragma unroll
            for (int r = 0; r < 4; ++r)
                op[(size_t)r*HW2] = acc[t][nn][r];
        }
}

extern "C" void kernel_launch(void* const* d_in, const int* in_sizes, int n_in,
                              void* d_out, int out_size, void* d_ws, size_t ws_size,
                              hipStream_t stream) {
    const float* x     = (const float*)d_in[0];
    const float* wcomp = (const float*)d_in[1];
    const float* wexp  = (const float*)d_in[2];
    const float* bw1   = (const float*)d_in[3];
    const float* bb1   = (const float*)d_in[4];
    const float* bw2   = (const float*)d_in[5];
    const float* bb2   = (const float*)d_in[6];
    const float* rw    = (const float*)d_in[7];
    const float* rb    = (const float*)d_in[8];
    const float* ow    = (const float*)d_in[9];
    const float* ob    = (const float*)d_in[10];
    float* out = (float*)d_out;
    float* ws  = (float*)d_ws;
    unsigned short* Mw = (unsigned short*)(ws + M_OFF);   // ~194 KB total used

    k1_mix<<<64, 256, 0, stream>>>(wcomp, wexp, bw1, bb1, bw2, bb2, rw, rb, ow, ob, ws);
    k1b_fold<<<64, 256, 0, stream>>>(ws, Mw);
    k2_mfma<<<2304, 256, 0, stream>>>(x, ws, Mw, out);
}